// Round 4
// baseline (701.107 us; speedup 1.0000x reference)
//
#include <hip/hip_runtime.h>

#define NNODES 12288
#define ETOT   73728
#define NGR    1024
#define LOG2E  1.442695041f
#define LN2    0.6931471806f

typedef __attribute__((ext_vector_type(8))) short short8;
typedef __attribute__((ext_vector_type(4))) float f32x4;

__device__ __forceinline__ unsigned short f2b(float f) {
  unsigned x = __float_as_uint(f);
  return (unsigned short)((x + 0x7FFFu + ((x >> 16) & 1u)) >> 16);
}
__device__ __forceinline__ float b2f(unsigned short u) {
  return __uint_as_float(((unsigned)u) << 16);
}
__device__ __forceinline__ void load_lds16(const void* g, void* l) {
  __builtin_amdgcn_global_load_lds(
      (const __attribute__((address_space(1))) unsigned int*)g,
      (__attribute__((address_space(3))) unsigned int*)l, 16, 0, 0);
}
__device__ __forceinline__ unsigned fenc(float f) {
  unsigned u = __float_as_uint(f);
  return (u & 0x80000000u) ? ~u : (u | 0x80000000u);
}
__device__ __forceinline__ float fdec(unsigned e) {
  unsigned u = (e & 0x80000000u) ? (e & 0x7FFFFFFFu) : ~e;
  return __uint_as_float(u);
}

// ---------------------------------------------------------------------------
// Pack (unchanged): transpose-convert all weights to bf16 [N][K].
// ---------------------------------------------------------------------------
__global__ void pack_kernel(
    const float* __restrict__ gat_Wl, const float* __restrict__ gat_Wr,
    const float* __restrict__ cg_Wf, const float* __restrict__ cg_Ws,
    const float* __restrict__ node_W, const float* __restrict__ enc_W,
    const float* __restrict__ fin_W1,
    const float* __restrict__ gat_bl, const float* __restrict__ gat_br,
    const float* __restrict__ cg_bf, const float* __restrict__ cg_bs,
    const float* __restrict__ x_my, const float* __restrict__ x_opp,
    unsigned short* __restrict__ wt_my, unsigned short* __restrict__ wt_opp,
    unsigned short* __restrict__ node_wt, unsigned short* __restrict__ enc_wt,
    unsigned short* __restrict__ fin_w1t,
    float* __restrict__ bias_my, float* __restrict__ bias_opp,
    unsigned short* __restrict__ xb)
{
  int idx = blockIdx.x * 256 + threadIdx.x;
  if (idx < 2 * 2359296) {
    int which = idx >= 2359296;
    int t = which ? idx - 2359296 : idx;
    int l = t / 786432;
    int r = t - l * 786432;
    int n = r >> 8, k = r & 255;
    float v;
    if (!which) {
      if (n < 1024)      v = gat_Wl[((l*2+0)*256 + k)*1024 + n];
      else if (n < 2048) v = gat_Wr[((l*2+1)*256 + k)*1024 + (n-1024)];
      else if (n < 2304) v = cg_Wf[((l*2+0)*512 + 256 + k)*256 + (n-2048)];
      else if (n < 2560) v = cg_Ws[((l*2+0)*512 + 256 + k)*256 + (n-2304)];
      else if (n < 2816) v = cg_Wf[((l*2+1)*512 + k)*256 + (n-2560)];
      else               v = cg_Ws[((l*2+1)*512 + k)*256 + (n-2816)];
      wt_my[t] = f2b(v);
    } else {
      if (n < 1024)      v = gat_Wr[((l*2+0)*256 + k)*1024 + n];
      else if (n < 2048) v = gat_Wl[((l*2+1)*256 + k)*1024 + (n-1024)];
      else if (n < 2304) v = cg_Wf[((l*2+0)*512 + k)*256 + (n-2048)];
      else if (n < 2560) v = cg_Ws[((l*2+0)*512 + k)*256 + (n-2304)];
      else if (n < 2816) v = cg_Wf[((l*2+1)*512 + 256 + k)*256 + (n-2560)];
      else               v = cg_Ws[((l*2+1)*512 + 256 + k)*256 + (n-2816)];
      wt_opp[t] = f2b(v);
    }
    return;
  }
  idx -= 2 * 2359296;
  if (idx < 196608) {
    int l = idx / 65536, r = idx - l * 65536;
    int n = r >> 8, k = r & 255;
    node_wt[idx] = f2b(node_W[(l*256 + k)*256 + n]);
    return;
  }
  idx -= 196608;
  if (idx < 8192) {
    int n = idx >> 5, k = idx & 31;
    enc_wt[idx] = f2b(enc_W[k*256 + n]);
    return;
  }
  idx -= 8192;
  if (idx < 32768) {
    int n = idx >> 8, k = idx & 255;
    fin_w1t[idx] = f2b(fin_W1[k*128 + n]);
    return;
  }
  idx -= 32768;
  if (idx < 9216) {
    int l = idx / 3072, n = idx - l * 3072;
    float v;
    if (n < 1024)      v = gat_bl[(l*2+0)*1024 + n];
    else if (n < 2048) v = gat_br[(l*2+1)*1024 + (n-1024)];
    else if (n < 2560) v = 0.f;
    else if (n < 2816) v = cg_bf[(l*2+1)*256 + (n-2560)];
    else               v = cg_bs[(l*2+1)*256 + (n-2816)];
    bias_my[idx] = v;
    return;
  }
  idx -= 9216;
  if (idx < 9216) {
    int l = idx / 3072, n = idx - l * 3072;
    float v;
    if (n < 1024)      v = gat_br[(l*2+0)*1024 + n];
    else if (n < 2048) v = gat_bl[(l*2+1)*1024 + (n-1024)];
    else if (n < 2304) v = cg_bf[(l*2+0)*256 + (n-2048)];
    else if (n < 2560) v = cg_bs[(l*2+0)*256 + (n-2304)];
    else               v = 0.f;
    bias_opp[idx] = v;
    return;
  }
  idx -= 9216;
  if (idx < 2 * 393216) {
    xb[idx] = f2b(idx < 393216 ? x_my[idx] : x_opp[idx - 393216]);
  }
}

// ---------------------------------------------------------------------------
// bf16 GEMM v2: 128x128 tile, BK=32, 4 waves, double-buffered LDS with
// prefetch-after-barrier (T3 minimum 2-phase), swapped-operand MFMA so each
// lane owns 4 consecutive C columns -> packed dwordx2 stores. Dual-source:
// blocks with blockIdx.x >= bx_split use the second pointer set.
// ---------------------------------------------------------------------------
__global__ __launch_bounds__(256) void gemm128(
    const unsigned short* __restrict__ A, const unsigned short* __restrict__ A2,
    int lda,
    const unsigned short* __restrict__ Wt, const unsigned short* __restrict__ Wt2,
    const float* __restrict__ bias, const float* __restrict__ bias2,
    unsigned short* __restrict__ C, unsigned short* __restrict__ C2,
    int ldc, int K, int act, int bx_split)
{
  __shared__ __align__(16) unsigned short lA[2][128 * 32];
  __shared__ __align__(16) unsigned short lB[2][128 * 32];
  const int tid = threadIdx.x;
  const int lane = tid & 63;
  const int w = tid >> 6;
  const int wr = w >> 1, wc = w & 1;
  const int tileN = blockIdx.y * 128;
  const int r0 = lane & 15;
  const int kq = lane >> 4;
  const int segr = (kq ^ ((r0 >> 1) & 3)) * 8;

  const unsigned short* Ap;
  const unsigned short* Wp;
  const float* bp;
  unsigned short* Cp;
  int tileM;
  if ((int)blockIdx.x < bx_split) {
    Ap = A;  Wp = Wt;  bp = bias;  Cp = C;  tileM = blockIdx.x * 128;
  } else {
    Ap = A2; Wp = Wt2; bp = bias2; Cp = C2; tileM = (blockIdx.x - bx_split) * 128;
  }

  f32x4 acc[4][4];
#pragma unroll
  for (int m = 0; m < 4; ++m)
#pragma unroll
    for (int n = 0; n < 4; ++n)
      acc[m][n] = (f32x4){0.f, 0.f, 0.f, 0.f};

  const int KT = K >> 5;
  // prologue: stage k-tile 0 into buffer 0
#pragma unroll
  for (int p = 0; p < 2; ++p) {
    int idx = p * 256 + tid;
    int rr = idx >> 2, sg = idx & 3;
    int ss = (sg ^ ((rr >> 1) & 3)) * 8;
    load_lds16(Ap + (size_t)(tileM + rr) * lda + ss, &lA[0][idx * 8]);
    load_lds16(Wp + (size_t)(tileN + rr) * K + ss, &lB[0][idx * 8]);
  }
  int cur = 0;
  for (int kt = 0; kt < KT; ++kt) {
    __syncthreads();                      // staged tile kt visible; prior reads done
    if (kt + 1 < KT) {                    // prefetch kt+1 (flies under compute)
      const int k0 = (kt + 1) * 32;
#pragma unroll
      for (int p = 0; p < 2; ++p) {
        int idx = p * 256 + tid;
        int rr = idx >> 2, sg = idx & 3;
        int ss = (sg ^ ((rr >> 1) & 3)) * 8;
        load_lds16(Ap + (size_t)(tileM + rr) * lda + k0 + ss, &lA[cur ^ 1][idx * 8]);
        load_lds16(Wp + (size_t)(tileN + rr) * K + k0 + ss, &lB[cur ^ 1][idx * 8]);
      }
    }
    short8 af[4], bfr[4];
#pragma unroll
    for (int m = 0; m < 4; ++m)
      af[m] = *(const short8*)&lA[cur][(wr * 64 + m * 16 + r0) * 32 + segr];
#pragma unroll
    for (int n = 0; n < 4; ++n)
      bfr[n] = *(const short8*)&lB[cur][(wc * 64 + n * 16 + r0) * 32 + segr];
#pragma unroll
    for (int m = 0; m < 4; ++m)
#pragma unroll
      for (int n = 0; n < 4; ++n)
        acc[m][n] = __builtin_amdgcn_mfma_f32_16x16x32_bf16(bfr[n], af[m], acc[m][n], 0, 0, 0);
    cur ^= 1;
  }
  // epilogue: lane holds rows tileM+wr*64+m*16+r0, cols n*16+kq*4..+3 -> dwordx2
#pragma unroll
  for (int m = 0; m < 4; ++m) {
    const int row = tileM + wr * 64 + m * 16 + r0;
    unsigned short* crow = Cp + (size_t)row * ldc;
#pragma unroll
    for (int n = 0; n < 4; ++n) {
      const int col0 = tileN + wc * 64 + n * 16 + kq * 4;
      const f32x4 bv = *(const f32x4*)&bp[col0];
      float v0 = acc[m][n][0] + bv[0];
      float v1 = acc[m][n][1] + bv[1];
      float v2 = acc[m][n][2] + bv[2];
      float v3 = acc[m][n][3] + bv[3];
      if (act) {
        v0 = v0 > 0.f ? v0 : 128.f * v0;
        v1 = v1 > 0.f ? v1 : 128.f * v1;
        v2 = v2 > 0.f ? v2 : 128.f * v2;
        v3 = v3 > 0.f ? v3 : 128.f * v3;
      }
      uint2 pk;
      pk.x = (unsigned)f2b(v0) | ((unsigned)f2b(v1) << 16);
      pk.y = (unsigned)f2b(v2) | ((unsigned)f2b(v3) << 16);
      *(uint2*)(crow + col0) = pk;
    }
  }
}

// ---------------------------------------------------------------------------
// GATv2 edge stage v3 (unchanged from R3): edge-parallel softmax, LDS atomics.
// ---------------------------------------------------------------------------
#define SX 260
__global__ __launch_bounds__(256) void gat_edge(
    const unsigned short* __restrict__ projS,
    const unsigned short* __restrict__ projD,
    const int* __restrict__ edges,
    const float* __restrict__ att,
    const float* __restrict__ gbias,
    float* __restrict__ outp)
{
  __shared__ __align__(16) unsigned short xl[48 * SX];
  __shared__ float attS[4 * SX];
  __shared__ float alphaS[288];
  __shared__ float wS[288];
  __shared__ unsigned mU[48];
  __shared__ float denS[48];
  __shared__ __align__(16) float A2f[12 * 48];
  __shared__ unsigned char se8[72], de8[72];
  const int g = blockIdx.x, tid = threadIdx.x;
  const int base = g * 12;

  if (tid < 72) {
    se8[tid] = (unsigned char)(edges[g * 72 + tid] - base);
    de8[tid] = (unsigned char)(edges[ETOT + g * 72 + tid] - base);
  }
  if (tid < 48) { mU[tid] = 0u; denS[tid] = 0.f; }
  for (int i = tid; i < 576; i += 256) A2f[i] = 0.f;
  for (int i = tid; i < 1024; i += 256)
    attS[(i >> 8) * SX + (i & 255)] = att[i];
  for (int i = tid; i < 3072; i += 256) {
    int s = i >> 8, c4 = (i & 255) * 4;
    int h = c4 >> 8, cc = c4 & 255;
    *(ushort4*)&xl[(h * 12 + s) * SX + cc] =
        *(const ushort4*)(projS + (size_t)(base + s) * 3072 + c4);
  }
  __syncthreads();

  for (int t = tid; t < 288; t += 256) {
    const int e = t >> 2, h = t & 3;
    const unsigned short* pl = &xl[(h * 12 + se8[e]) * SX];
    const unsigned short* pr = projD + (size_t)(base + de8[e]) * 3072 + h * 256;
    const f32x4* pa = (const f32x4*)&attS[h * SX];
    float sum = 0.f;
    for (int q = 0; q < 64; ++q) {
      ushort4 a4 = *(const ushort4*)(pl + q * 4);
      ushort4 b4 = *(const ushort4*)(pr + q * 4);
      f32x4 av = pa[q];
      float v0 = b2f(a4.x) + b2f(b4.x); v0 = fmaxf(v0, 0.2f * v0);
      float v1 = b2f(a4.y) + b2f(b4.y); v1 = fmaxf(v1, 0.2f * v1);
      float v2 = b2f(a4.z) + b2f(b4.z); v2 = fmaxf(v2, 0.2f * v2);
      float v3 = b2f(a4.w) + b2f(b4.w); v3 = fmaxf(v3, 0.2f * v3);
      sum = fmaf(v0, av.x, sum); sum = fmaf(v1, av.y, sum);
      sum = fmaf(v2, av.z, sum); sum = fmaf(v3, av.w, sum);
    }
    sum *= LOG2E;
    alphaS[t] = sum;
    atomicMax(&mU[de8[e] * 4 + h], fenc(sum));
  }
  __syncthreads();

  for (int t = tid; t < 288; t += 256) {
    const int e = t >> 2, h = t & 3;
    const float m = fdec(mU[de8[e] * 4 + h]);
    const float wv = __builtin_amdgcn_exp2f(alphaS[t] - m);
    wS[t] = wv;
    atomicAdd(&denS[de8[e] * 4 + h], wv);
  }
  __syncthreads();

  for (int t = tid; t < 288; t += 256) {
    const int e = t >> 2, h = t & 3;
    const float inv = 0.25f * __builtin_amdgcn_rcpf(denS[de8[e] * 4 + h] + 1e-16f);
    atomicAdd(&A2f[de8[e] * 48 + h * 12 + se8[e]], wS[t] * inv);
  }
  __syncthreads();

  {
    const int c = tid;
    float xlv[48];
#pragma unroll
    for (int j = 0; j < 48; ++j) xlv[j] = b2f(xl[j * SX + c]);
    const float gb = gbias[c];
#pragma unroll
    for (int d = 0; d < 12; ++d) {
      const f32x4* arow = (const f32x4*)&A2f[d * 48];
      float s = 0.f;
#pragma unroll
      for (int jj = 0; jj < 12; ++jj) {
        f32x4 a4 = arow[jj];
        s = fmaf(a4.x, xlv[jj * 4 + 0], s);
        s = fmaf(a4.y, xlv[jj * 4 + 1], s);
        s = fmaf(a4.z, xlv[jj * 4 + 2], s);
        s = fmaf(a4.w, xlv[jj * 4 + 3], s);
      }
      outp[(size_t)(base + d) * 256 + c] = s + gb;
    }
  }
}

// ---------------------------------------------------------------------------
// CGConv edge stage (unchanged).
// ---------------------------------------------------------------------------
__global__ __launch_bounds__(256) void cg_edge(
    const unsigned short* __restrict__ pdF, const unsigned short* __restrict__ pdS,
    const unsigned short* __restrict__ psF, const unsigned short* __restrict__ psS,
    const unsigned short* __restrict__ hres,
    const float* __restrict__ gatp,
    const int* __restrict__ edges,
    unsigned short* __restrict__ outp)
{
  __shared__ __align__(8) unsigned short df[3072], dsb[3072];
  __shared__ __align__(8) unsigned short sfb[3072], ssb[3072];
  __shared__ unsigned char srcl[12 * 80];
  __shared__ int cnt[12];
  __shared__ int se_[72], de_[72];
  const int g = blockIdx.x, tid = threadIdx.x;
  const int base = g * 12;
  if (tid < 72) {
    se_[tid] = edges[g * 72 + tid] - base;
    de_[tid] = edges[ETOT + g * 72 + tid] - base;
  }
  for (int i = tid; i < 768; i += 256) {
    int s = i >> 6, c4 = (i & 63) * 4;
    size_t gb = (size_t)(base + s) * 3072 + c4;
    *(ushort4*)&df[s * 256 + c4]  = *(const ushort4*)(pdF + gb);
    *(ushort4*)&dsb[s * 256 + c4] = *(const ushort4*)(pdS + gb);
    *(ushort4*)&sfb[s * 256 + c4] = *(const ushort4*)(psF + gb);
    *(ushort4*)&ssb[s * 256 + c4] = *(const ushort4*)(psS + gb);
  }
  __syncthreads();
  if (tid < 12) {
    int n = 0;
    for (int e = 0; e < 72; ++e)
      if (de_[e] == tid) srcl[tid * 80 + (n++)] = (unsigned char)se_[e];
    cnt[tid] = n;
  }
  __syncthreads();
  const int c = tid;
  for (int d = 0; d < 12; ++d) {
    const float fd = b2f(df[d * 256 + c]);
    const float sd = b2f(dsb[d * 256 + c]);
    const int n = cnt[d];
    float acc = 0.f;
    for (int j = 0; j < n; ++j) {
      const int s = srcl[d * 80 + j];
      const float zf = fd + b2f(sfb[s * 256 + c]);
      const float zs = sd + b2f(ssb[s * 256 + c]);
      const float gate = __builtin_amdgcn_rcpf(1.f + __builtin_amdgcn_exp2f(-LOG2E * zf));
      const float e2 = __builtin_amdgcn_exp2f(-LOG2E * fabsf(zs));
      const float sp = fmaxf(zs, 0.f) + LN2 * __builtin_amdgcn_logf(1.f + e2);
      acc = fmaf(gate, sp, acc);
    }
    const size_t o = (size_t)(base + d) * 256 + c;
    outp[o] = f2b(b2f(hres[o]) + gatp[o] + acc);
  }
}

// ---------------------------------------------------------------------------
// logits: one wave per node, dot(f[128], W2) + b2
// ---------------------------------------------------------------------------
__global__ __launch_bounds__(256) void logits_kernel(
    const unsigned short* __restrict__ f, const float* __restrict__ W2,
    const float* __restrict__ b2, float* __restrict__ out)
{
  const int node = blockIdx.x * 4 + (threadIdx.x >> 6);
  const int lane = threadIdx.x & 63;
  const size_t o = (size_t)node * 128 + lane * 2;
  float s = b2f(f[o]) * W2[lane * 2] + b2f(f[o + 1]) * W2[lane * 2 + 1];
  for (int d = 32; d > 0; d >>= 1) s += __shfl_down(s, d, 64);
  if (lane == 0) out[node] = s + b2[0];
}

// ---------------------------------------------------------------------------
extern "C" void kernel_launch(void* const* d_in, const int* in_sizes, int n_in,
                              void* d_out, int out_size, void* d_ws, size_t ws_size,
                              hipStream_t stream) {
  const float* x_my    = (const float*)d_in[0];
  const float* x_opp   = (const float*)d_in[1];
  const int*   e_beats = (const int*)d_in[2];
  const int*   e_loses = (const int*)d_in[3];
  const int*   e_rb    = (const int*)d_in[4];
  const int*   e_rl    = (const int*)d_in[5];
  const float* enc_W   = (const float*)d_in[7];
  const float* enc_b   = (const float*)d_in[8];
  const float* gat_Wl  = (const float*)d_in[9];
  const float* gat_bl  = (const float*)d_in[10];
  const float* gat_Wr  = (const float*)d_in[11];
  const float* gat_br  = (const float*)d_in[12];
  const float* gat_att = (const float*)d_in[13];
  const float* gat_bsp = (const float*)d_in[14];
  const float* cg_Wf   = (const float*)d_in[15];
  const float* cg_bf   = (const float*)d_in[16];
  const float* cg_Ws   = (const float*)d_in[17];
  const float* cg_bs   = (const float*)d_in[18];
  const float* node_W  = (const float*)d_in[19];
  const float* node_b  = (const float*)d_in[20];
  const float* fin_W1  = (const float*)d_in[21];
  const float* fin_b1  = (const float*)d_in[22];
  const float* fin_W2  = (const float*)d_in[23];
  const float* fin_b2  = (const float*)d_in[24];

  char* wsp = (char*)d_ws;
  size_t off = 0;
  auto alloc = [&](size_t b) { char* p = wsp + off; off += (b + 255) & ~(size_t)255; return p; };
  unsigned short* wt_my   = (unsigned short*)alloc((size_t)2359296 * 2);
  unsigned short* wt_opp  = (unsigned short*)alloc((size_t)2359296 * 2);
  unsigned short* node_wt = (unsigned short*)alloc((size_t)196608 * 2);
  unsigned short* enc_wt  = (unsigned short*)alloc((size_t)8192 * 2);
  unsigned short* fin_w1t = (unsigned short*)alloc((size_t)32768 * 2);
  float*          bias_my = (float*)alloc((size_t)9216 * 4);
  float*          bias_op = (float*)alloc((size_t)9216 * 4);
  unsigned short* xb      = (unsigned short*)alloc((size_t)786432 * 2);
  unsigned short* Hb      = (unsigned short*)alloc((size_t)2 * NNODES * 256 * 2);
  unsigned short* proj_my = (unsigned short*)alloc((size_t)NNODES * 3072 * 2);
  unsigned short* proj_op = (unsigned short*)alloc((size_t)NNODES * 3072 * 2);
  float*          gat_my  = (float*)alloc((size_t)NNODES * 256 * 4);
  float*          gat_op  = (float*)alloc((size_t)NNODES * 256 * 4);
  unsigned short* node_in = (unsigned short*)alloc((size_t)2 * NNODES * 256 * 2);
  unsigned short* fbuf    = (unsigned short*)alloc((size_t)NNODES * 128 * 2);

  const int PACK_TOTAL = 2 * 2359296 + 196608 + 8192 + 32768 + 2 * 9216 + 2 * 393216;
  pack_kernel<<<(PACK_TOTAL + 255) / 256, 256, 0, stream>>>(
      gat_Wl, gat_Wr, cg_Wf, cg_Ws, node_W, enc_W, fin_W1,
      gat_bl, gat_br, cg_bf, cg_bs, x_my, x_opp,
      wt_my, wt_opp, node_wt, enc_wt, fin_w1t, bias_my, bias_op, xb);

  unsigned short* Hmy   = Hb;
  unsigned short* Hopp  = Hb + (size_t)NNODES * 256;
  unsigned short* ni_my = node_in;
  unsigned short* ni_op = node_in + (size_t)NNODES * 256;

  // encoder: h = x @ enc_W + enc_b  (M = 2N, K = 32)
  gemm128<<<dim3(192, 2), 256, 0, stream>>>(
      xb, xb, 32, enc_wt, enc_wt, enc_b, enc_b, Hb, Hb, 256, 32, 0, 192);

  for (int l = 0; l < 3; ++l) {
    // both proj GEMMs in one dispatch (x-blocks 0..95 = my, 96..191 = opp)
    gemm128<<<dim3(192, 24), 256, 0, stream>>>(
        Hmy, Hopp, 256,
        wt_my + (size_t)l * 786432, wt_opp + (size_t)l * 786432,
        bias_my + l * 3072, bias_op + l * 3072,
        proj_my, proj_op, 3072, 256, 0, 96);
    gat_edge<<<NGR, 256, 0, stream>>>(proj_my, proj_op, e_beats,
                                      gat_att + (l * 2 + 0) * 1024,
                                      gat_bsp + (l * 2 + 0) * 256, gat_op);
    gat_edge<<<NGR, 256, 0, stream>>>(proj_op + 1024, proj_my + 1024, e_rl,
                                      gat_att + (l * 2 + 1) * 1024,
                                      gat_bsp + (l * 2 + 1) * 256, gat_my);
    cg_edge<<<NGR, 256, 0, stream>>>(proj_op + 2048, proj_op + 2304,
                                     proj_my + 2048, proj_my + 2304,
                                     Hopp, gat_op, e_loses, ni_op);
    cg_edge<<<NGR, 256, 0, stream>>>(proj_my + 2560, proj_my + 2816,
                                     proj_op + 2560, proj_op + 2816,
                                     Hmy, gat_my, e_rb, ni_my);
    gemm128<<<dim3(192, 2), 256, 0, stream>>>(
        node_in, node_in, 256, node_wt + (size_t)l * 65536, node_wt + (size_t)l * 65536,
        node_b + l * 256, node_b + l * 256, Hb, Hb, 256, 256, 0, 192);
  }

  gemm128<<<dim3(96, 1), 256, 0, stream>>>(
      Hmy, Hmy, 256, fin_w1t, fin_w1t, fin_b1, fin_b1, fbuf, fbuf, 128, 256, 1, 96);
  logits_kernel<<<NNODES / 4, 256, 0, stream>>>(fbuf, fin_W2, fin_b2, (float*)d_out);
}